// Round 5
// baseline (617.624 us; speedup 1.0000x reference)
//
#include <hip/hip_runtime.h>
#include <math.h>

// Problem constants
// x: (B=2, C=32, D=96, H=96, W=96) fp32
// out: (2, 32, 48, 48, 48) fp32
#define HS 0.35355339059327373f   /* 1/(2*sqrt(2)) — 3-stage Haar scale */
#define NSPAT 110592              /* 48^3 */
#define NBN   221184              /* B * 48^3 */

// ---------------------------------------------------------------------------
// K1: per-(b,c) parity sums S[b][c][p][q][r] = sum over x[2i+p][2j+q][2l+r]
// One block per (b,c,d)-plane: 96*96 floats = 2304 float4s, 256 thr * 9.
// (unchanged — streams x once at ~HBM floor, ~36-50 us)
// ---------------------------------------------------------------------------
__global__ __launch_bounds__(256) void k1_parity(const float* __restrict__ x,
                                                 float* __restrict__ S) {
    int blk = blockIdx.x;            // (b*32+c)*96 + d
    int d   = blk % 96;
    int bc  = blk / 96;
    const float4* x4 = (const float4*)x + (long)blk * 2304;
    int tid = threadIdx.x;
    float aE0 = 0.f, aO0 = 0.f, aE1 = 0.f, aO1 = 0.f;  // [q][r]
#pragma unroll
    for (int i = 0; i < 9; ++i) {
        int f = tid + i * 256;           // < 2304
        float4 v = x4[f];
        int h = f / 24;                  // row within plane (const-div -> magic mul)
        float e = v.x + v.z, o = v.y + v.w;
        if (h & 1) { aE1 += e; aO1 += o; }
        else       { aE0 += e; aO0 += o; }
    }
#pragma unroll
    for (int m = 32; m; m >>= 1) {
        aE0 += __shfl_xor(aE0, m, 64); aO0 += __shfl_xor(aO0, m, 64);
        aE1 += __shfl_xor(aE1, m, 64); aO1 += __shfl_xor(aO1, m, 64);
    }
    __shared__ float red[4][4];
    int lane = tid & 63, wave = tid >> 6;
    if (lane == 0) { red[wave][0] = aE0; red[wave][1] = aO0;
                     red[wave][2] = aE1; red[wave][3] = aO1; }
    __syncthreads();
    if (tid < 4) {
        float v = red[0][tid] + red[1][tid] + red[2][tid] + red[3][tid];
        int q = tid >> 1, r = tid & 1, p = d & 1;
        atomicAdd(&S[bc * 8 + p * 4 + q * 2 + r], v);
    }
}

// ---------------------------------------------------------------------------
// K2: band means -> two attention MLPs -> effective fuse matrix.
// 16 blocks (b x 8 slices); MLP recomputed redundantly per block (tiny);
// all dots lane-parallel + shfl tree reduce; A-write sliced 8-way.
// A layout: A[b][c][o][pqr] — per-(c,og) contiguous 512 B, so K3 can stage
// its og-slice into LDS with plain float4 loads.
// ---------------------------------------------------------------------------
__global__ __launch_bounds__(256) void k2_attn(
        const float* __restrict__ S,
        const float* __restrict__ w1l, const float* __restrict__ w2l,
        const float* __restrict__ w1h, const float* __restrict__ w2h,
        const float* __restrict__ wf, float* __restrict__ A) {
    int b = blockIdx.x >> 3, slice = blockIdx.x & 7;
    int tid = threadIdx.x;
    __shared__ float mlow[32], mhigh[224], h1l[2], h1h[14], ylow[32], yhigh[224];
    const float* Sb = S + b * 256;
    const float MS = HS / (float)NSPAT;   // subband mean scale

    // subband means: 256 lanes, one (c, band) each. k=0 -> low, k>=1 -> detail k-1
    {
        int c = tid >> 3, k = tid & 7;
        float s = 0.f;
        if (k == 0) {
#pragma unroll
            for (int j = 0; j < 8; ++j) s += Sb[c * 8 + j];
            mlow[c] = s * MS;
        } else {
#pragma unroll
            for (int j = 0; j < 8; ++j) {
                float sg = (__popc(j & k) & 1) ? -1.f : 1.f;
                s += sg * Sb[c * 8 + j];
            }
            mhigh[c * 7 + (k - 1)] = s * MS;
        }
    }
    __syncthreads();
    // hidden layers: lane-parallel dots + 16-lane shfl tree reduce
    if (tid < 224) {            // h1h[g] = relu(w1h[g,:224] . mhigh)
        int g = tid >> 4, l = tid & 15;
        float p = 0.f;
#pragma unroll
        for (int i = 0; i < 14; ++i)
            p += w1h[g * 224 + l * 14 + i] * mhigh[l * 14 + i];
#pragma unroll
        for (int m = 8; m; m >>= 1) p += __shfl_xor(p, m, 64);
        if (l == 0) h1h[g] = fmaxf(p, 0.f);
    } else {                    // tid in [224,256): h1l[j] = relu(w1l[j,:32] . mlow)
        int j = (tid - 224) >> 4, l = tid & 15;
        float p = w1l[j * 32 + l] * mlow[l] + w1l[j * 32 + 16 + l] * mlow[16 + l];
#pragma unroll
        for (int m = 8; m; m >>= 1) p += __shfl_xor(p, m, 64);
        if (l == 0) h1l[j] = fmaxf(p, 0.f);
    }
    __syncthreads();
    if (tid < 32) {
        float s = w2l[tid * 2] * h1l[0] + w2l[tid * 2 + 1] * h1l[1];
        ylow[tid] = 1.f / (1.f + expf(-s));
    } else {
        int i = tid - 32;       // < 224
        float s = 0.f;
#pragma unroll
        for (int j = 0; j < 14; ++j) s += w2h[i * 14 + j] * h1h[j];
        yhigh[i] = 1.f / (1.f + expf(-s));
    }
    __syncthreads();
    // A-write, sliced 8-way across blocks; layout [b][c][o][pqr]
#pragma unroll
    for (int it = 0; it < 4; ++it) {
        int idx = slice * 1024 + it * 256 + tid;       // < 8192
        int o = idx >> 8, c = (idx >> 3) & 31, pqr = idx & 7;
        float a = wf[o * 256 + c] * ylow[c];
#pragma unroll
        for (int k = 0; k < 7; ++k) {
            float sg = (__popc(pqr & (k + 1)) & 1) ? -1.f : 1.f;
            a += sg * wf[o * 256 + 32 + c * 7 + k] * yhigh[c * 7 + k];
        }
        A[b * 8192 + c * 256 + o * 8 + pqr] = a * HS;
    }
}

// ---------------------------------------------------------------------------
// K3 (main): z[b,o,od,oh,ow] = sum_{c,pqr} A[b,o,c,pqr] * x[b,c,2od+p,2oh+q,2ow+r]
// R8 post-mortem of R7 (k3 ~112us, floor ~23us): the LDS-A loop issued
// 2 ds_read_b128 per 16 FMAs (1:2 A:FMA issue ratio) and per-thread work
// was too small to amortize it. Fix = amortization:
//  - 4 output pixels per thread (ow = 4t..4t+3): FMAs/thread 8192->16384,
//    A-reads unchanged -> 16:1 FMA:ds ratio; z-write becomes full float4.
//  - __launch_bounds__(192, 2): 256-VGPR budget; prevents the compiler's
//    default heuristic from capping at 64 VGPR + spilling (seen in R6).
//    Needs ~150: acc[16][4]=64 + ping-pong 16 float4 = 64 + addressing.
//  - block 192 = 16 rows x 12 t; grid 576 = b(2) x od(48) x ohg(3) x og(2).
//  - A og-slice (16 KB) in LDS, uniform ds_read broadcasts (conflict-free).
//  - XCD-twin swizzle: og twins (same x-slab) land on same XCD L2.
// ---------------------------------------------------------------------------
#define K3_LOAD(s, cc) { int i4_ = base + (cc) * 221184;                     \
    s##0 = x4[i4_];        s##1 = x4[i4_ + 1];                               \
    s##2 = x4[i4_ + 24];   s##3 = x4[i4_ + 25];                              \
    s##4 = x4[i4_ + 2304]; s##5 = x4[i4_ + 2305];                            \
    s##6 = x4[i4_ + 2328]; s##7 = x4[i4_ + 2329]; }

// s0/s1: (p0,q0) w-lo/hi; s2/s3: (p0,q1); s4/s5: (p1,q0); s6/s7: (p1,q1)
#define K3_FMA(s, Ac) {                                                      \
    _Pragma("unroll")                                                        \
    for (int o = 0; o < 16; ++o) {                                           \
        const float* Ao_ = (Ac) + o * 8;   /* uniform LDS broadcast */       \
        float a0 = Ao_[0], a1 = Ao_[1], a2 = Ao_[2], a3 = Ao_[3];            \
        float a4 = Ao_[4], a5 = Ao_[5], a6 = Ao_[6], a7 = Ao_[7];            \
        acc[o][0] += a0 * (s##0).x + a1 * (s##0).y + a2 * (s##2).x           \
                   + a3 * (s##2).y + a4 * (s##4).x + a5 * (s##4).y           \
                   + a6 * (s##6).x + a7 * (s##6).y;                          \
        acc[o][1] += a0 * (s##0).z + a1 * (s##0).w + a2 * (s##2).z           \
                   + a3 * (s##2).w + a4 * (s##4).z + a5 * (s##4).w           \
                   + a6 * (s##6).z + a7 * (s##6).w;                          \
        acc[o][2] += a0 * (s##1).x + a1 * (s##1).y + a2 * (s##3).x           \
                   + a3 * (s##3).y + a4 * (s##5).x + a5 * (s##5).y           \
                   + a6 * (s##7).x + a7 * (s##7).y;                          \
        acc[o][3] += a0 * (s##1).z + a1 * (s##1).w + a2 * (s##3).z           \
                   + a3 * (s##3).w + a4 * (s##5).z + a5 * (s##5).w           \
                   + a6 * (s##7).z + a7 * (s##7).w;                          \
    } }

__global__ __launch_bounds__(192, 2) void k3_main(const float* __restrict__ x,
                                                  const float* __restrict__ A,
                                                  float* __restrict__ z,
                                                  float* __restrict__ bnSum,
                                                  float* __restrict__ bnSq) {
    __shared__ float sA[4096];         // og-slice: [c<32][o'<16][pqr<8]
    __shared__ float red[3][32];
    int blk  = blockIdx.x;             // [resthi | og(1b) | restlo(3b)]
    int og   = (blk >> 3) & 1;
    int rest = (blk & 7) | ((blk >> 4) << 3);   // 0..287
    int ohg  = rest % 3;
    int tmp  = rest / 3;
    int od   = tmp % 48;
    int b    = tmp / 48;
    int tid = threadIdx.x;
    int row = tid / 12;                // 0..15
    int t   = tid % 12;                // ow quad: outputs 4t..4t+3
    int oh  = ohg * 16 + row;

    const float4* x4 = (const float4*)x;
    // float4 index for (b, c, 2od+p, 2oh+q, 8t): channel stride 96^3/4 = 221184
    int base = (((b * 32) * 96 + 2 * od) * 96 + 2 * oh) * 24 + 2 * t;

    // stage A og-slice into LDS: sA[c*128 + o'*8 + pqr] = A[b][c][og*16+o'][pqr]
    {
        const float4* A4 = (const float4*)A;
        int srcbase = b * 2048 + og * 32;     // float4 units
        float4* sA4 = (float4*)sA;
        for (int s = tid; s < 1024; s += 192) {
            int c = s >> 5, j = s & 31;
            sA4[s] = A4[srcbase + c * 64 + j];
        }
    }

    float acc[16][4];
#pragma unroll
    for (int o = 0; o < 16; ++o) {
        acc[o][0] = 0.f; acc[o][1] = 0.f; acc[o][2] = 0.f; acc[o][3] = 0.f;
    }

    float4 pa0, pa1, pa2, pa3, pa4, pa5, pa6, pa7;
    float4 pb0, pb1, pb2, pb3, pb4, pb5, pb6, pb7;
    K3_LOAD(pa, 0);                    // x prefetch overlaps A staging
    __syncthreads();

    for (int c = 0; c < 32; c += 2) {
        K3_LOAD(pb, c + 1);
        const float* Ac = sA + c * 128;
        K3_FMA(pa, Ac);
        if (c + 2 < 32) K3_LOAD(pa, c + 2);
        K3_FMA(pb, Ac + 128);
    }

    // write z (staged in d_out), coalesced float4 per o
    float4* z4g = (float4*)z;
#pragma unroll
    for (int o = 0; o < 16; ++o) {
        int zi = (((b * 32 + og * 16 + o) * 48 + od) * 48 + oh) * 12 + t;
        z4g[zi] = make_float4(acc[o][0], acc[o][1], acc[o][2], acc[o][3]);
    }

    // BN partial sums for this block's 16 channels
    int lane = tid & 63, wave = tid >> 6;
#pragma unroll
    for (int o = 0; o < 16; ++o) {
        float sv = acc[o][0] + acc[o][1] + acc[o][2] + acc[o][3];
        float qv = acc[o][0] * acc[o][0] + acc[o][1] * acc[o][1]
                 + acc[o][2] * acc[o][2] + acc[o][3] * acc[o][3];
#pragma unroll
        for (int m = 32; m; m >>= 1) {
            sv += __shfl_xor(sv, m, 64);
            qv += __shfl_xor(qv, m, 64);
        }
        if (lane == 0) { red[wave][o] = sv; red[wave][16 + o] = qv; }
    }
    __syncthreads();
    if (tid < 32) {
        float v = red[0][tid] + red[1][tid] + red[2][tid];
        if (tid < 16) atomicAdd(&bnSum[og * 16 + tid], v);
        else          atomicAdd(&bnSq[og * 16 + tid - 16], v);
    }
}

// ---------------------------------------------------------------------------
// K5: BN finalize (per-block recompute) + normalize + ReLU, in place over
// z (= d_out). 1769472 float4s exactly. b_fuse cancels under BN mean-subtract.
// ---------------------------------------------------------------------------
__global__ __launch_bounds__(256) void k5_norm(float* __restrict__ z,
                                               const float* __restrict__ bnSum,
                                               const float* __restrict__ bnSq,
                                               const float* __restrict__ gamma,
                                               const float* __restrict__ beta) {
    __shared__ float s_sc[32], s_sh[32];
    int tid = threadIdx.x;
    if (tid < 32) {
        const float invN = 1.f / (float)NBN;
        float mean = bnSum[tid] * invN;
        float var  = bnSq[tid] * invN - mean * mean;
        float inv  = rsqrtf(var + 1e-5f);
        float sc   = gamma[tid] * inv;
        s_sc[tid] = sc;
        s_sh[tid] = beta[tid] - mean * sc;
    }
    int i = blockIdx.x * 256 + tid;                // float4 index
    float4* z4 = (float4*)z;
    float4 v = z4[i];                              // load before barrier (indep)
    __syncthreads();
    int o = (i / 27648) & 31;                      // 27648 = 48^3/4
    float sc = s_sc[o], sh = s_sh[o];
    v.x = fmaxf(v.x * sc + sh, 0.f);
    v.y = fmaxf(v.y * sc + sh, 0.f);
    v.z = fmaxf(v.z * sc + sh, 0.f);
    v.w = fmaxf(v.w * sc + sh, 0.f);
    z4[i] = v;
}

extern "C" void kernel_launch(void* const* d_in, const int* in_sizes, int n_in,
                              void* d_out, int out_size, void* d_ws, size_t ws_size,
                              hipStream_t stream) {
    const float* x    = (const float*)d_in[0];
    const float* w1l  = (const float*)d_in[1];
    const float* w2l  = (const float*)d_in[2];
    const float* w1h  = (const float*)d_in[3];
    const float* w2h  = (const float*)d_in[4];
    const float* wf   = (const float*)d_in[5];
    // d_in[6] = b_fuse: cancels exactly under training-mode BN (mean subtract)
    const float* gamma = (const float*)d_in[7];
    const float* beta  = (const float*)d_in[8];
    float* out = (float*)d_out;

    float* ws    = (float*)d_ws;
    float* S     = ws;          // 512 floats (zeroed)
    float* bnSum = ws + 512;    // 32 (zeroed)
    float* bnSq  = ws + 544;    // 32 (zeroed)
    float* A     = ws + 1024;   // 16384 floats, layout [b][c][o][pqr]

    hipMemsetAsync(d_ws, 0, 576 * sizeof(float), stream);
    k1_parity<<<6144, 256, 0, stream>>>(x, S);
    k2_attn<<<16, 256, 0, stream>>>(S, w1l, w2l, w1h, w2h, wf, A);
    k3_main<<<576, 192, 0, stream>>>(x, A, out, bnSum, bnSq);
    k5_norm<<<6912, 256, 0, stream>>>(out, bnSum, bnSq, gamma, beta);
}